// Round 1
// 731.003 us; speedup vs baseline: 1.1203x; 1.1203x over previous
//
#include <hip/hip_runtime.h>

// ScaledDotProductAttention with per-neighbor prior reweighting + mask.
// Shapes: q,k,v [N=65536, L=20, D=64] f32; r_pri [B=32768, L]; mask [N, L] (int).
// out = concat(output [N,D], attn [N,L]) f32.
//
// One 64-lane wave per row n. lane = grp*16 + sub.
//   chunk c in [0,5): l = 4c + grp; float4 index = 64c + lane -> each wave-load
//   covers 4 consecutive l-rows = 1024 contiguous bytes. Fully coalesced.
//
// R3: mask-predicated loads. mask = Bernoulli(0.5); a masked l has w[l] == 0
// EXACTLY in f32 (exp(-1e10 - m) underflows for any finite m from unmasked
// entries), so q[l], k[l], v[l] are never needed. Load mask (5 MB, L3-resident)
// first, then issue q/k/v loads only for unmasked l-rows. Cuts the required
// input stream from ~1.01 GB to ~0.52 GB. Predicate is uniform per 16-lane
// group -> exec-masked lanes skip whole 256 B (4 cache-line) slices.
//
// Edge case: a fully-masked row (ballot == 0) has uniform softmax w = 1/20 and
// needs ALL of v (but still no q/k: x[c] = NEG_INF regardless, and
// (-1e10) - (-1e10) = 0 -> w = exp(0) = 1, s = 20). v-predicate widened there.

namespace {
constexpr int kL = 20;
constexpr int kD = 64;
constexpr int kB = 32768;
constexpr float kNegInf = -1e10f;
constexpr float kInvTemp = 0.125f;  // 1 / TEMPERATURE(=8)
}

__global__ __launch_bounds__(256) void sdpa_prior_mask_kernel(
    const float* __restrict__ q,
    const float* __restrict__ k,
    const float* __restrict__ v,
    const float* __restrict__ r_pri,
    const int* __restrict__ mask,
    float* __restrict__ out,       // [N, D]
    float* __restrict__ attn_out,  // [N, L]
    int N)
{
    const int wave = threadIdx.x >> 6;
    const int lane = threadIdx.x & 63;
    const int n = blockIdx.x * 4 + wave;
    if (n >= N) return;

    const int sub = lane & 15;  // which float4 within the 64-wide d-row
    const int grp = lane >> 4;  // l offset within a 4-row chunk

    const size_t row_base = (size_t)n * kL * kD;
    const float4* qb = (const float4*)(q + row_base);
    const float4* kb = (const float4*)(k + row_base);
    const float4* vb = (const float4*)(v + row_base);
    const int b = n & (kB - 1);
    const float* rp = r_pri + (size_t)b * kL;
    const int* mk = mask + (size_t)n * kL;

    // ---- mask + prior first (tiny, L3-resident: gates everything else) ----
    float rpl[5];
    int mkl[5];
#pragma unroll
    for (int c = 0; c < 5; ++c) {
        const int l = 4 * c + grp;
        mkl[c] = mk[l];
        rpl[c] = rp[l];
    }

    bool any_unmasked = false;
#pragma unroll
    for (int c = 0; c < 5; ++c) any_unmasked |= (mkl[c] == 0);
    const bool all_masked = (__ballot(any_unmasked) == 0ull);

    // ---- predicated q/k loads: only unmasked l-rows contribute logits ----
    float4 qv[5], kv[5];
#pragma unroll
    for (int c = 0; c < 5; ++c) {
        qv[c] = make_float4(0.f, 0.f, 0.f, 0.f);
        kv[c] = make_float4(0.f, 0.f, 0.f, 0.f);
        if (mkl[c] == 0) {
            const int idx = 64 * c + lane;
            qv[c] = qb[idx];
            kv[c] = kb[idx];
        }
    }

    // ---- logits: x[c] = masked, scaled dot(q[l], k[l]) for l = 4c + grp ----
    // (zeros for masked groups flow through the uniform-exec shuffles harmlessly)
    float x[5];
#pragma unroll
    for (int c = 0; c < 5; ++c) {
        float p = qv[c].x * kv[c].x + qv[c].y * kv[c].y +
                  qv[c].z * kv[c].z + qv[c].w * kv[c].w;
        // reduce across the 16 sub-lanes (same l)
        p += __shfl_xor(p, 1);
        p += __shfl_xor(p, 2);
        p += __shfl_xor(p, 4);
        p += __shfl_xor(p, 8);
        const float scaled = p * rpl[c] * kInvTemp;
        x[c] = (mkl[c] != 0) ? kNegInf : scaled;
    }

    // ---- predicated v loads, issued BEFORE the softmax shuffle chain so their
    // latency hides under it (q/k registers are dead after the logit loop) ----
    float4 vv[5];
#pragma unroll
    for (int c = 0; c < 5; ++c) {
        vv[c] = make_float4(0.f, 0.f, 0.f, 0.f);
        if ((mkl[c] == 0) || all_masked) {
            vv[c] = vb[64 * c + lane];
        }
    }

    // ---- softmax over all 20 l (each lane holds 5; union over 4 grps = 20) ----
    float m = x[0];
#pragma unroll
    for (int c = 1; c < 5; ++c) m = fmaxf(m, x[c]);
    m = fmaxf(m, __shfl_xor(m, 16));
    m = fmaxf(m, __shfl_xor(m, 32));

    float w[5];
    float s = 0.f;
#pragma unroll
    for (int c = 0; c < 5; ++c) {
        w[c] = __expf(x[c] - m);
        s += w[c];
    }
    s += __shfl_xor(s, 16);
    s += __shfl_xor(s, 32);
    const float inv_s = 1.0f / s;
#pragma unroll
    for (int c = 0; c < 5; ++c) w[c] *= inv_s;

    // ---- output: out[n, d] = sum_l w[l] * v[n, l, d] ----
    // (skipped v rows have w == 0 and vv == 0: contribute nothing, no NaNs)
    float4 acc = {0.f, 0.f, 0.f, 0.f};
#pragma unroll
    for (int c = 0; c < 5; ++c) {
        acc.x += w[c] * vv[c].x;
        acc.y += w[c] * vv[c].y;
        acc.z += w[c] * vv[c].z;
        acc.w += w[c] * vv[c].w;
    }
    // sum partial outputs across the 4 grps (same d-range, different l-sets)
    acc.x += __shfl_xor(acc.x, 16);
    acc.x += __shfl_xor(acc.x, 32);
    acc.y += __shfl_xor(acc.y, 16);
    acc.y += __shfl_xor(acc.y, 32);
    acc.z += __shfl_xor(acc.z, 16);
    acc.z += __shfl_xor(acc.z, 32);
    acc.w += __shfl_xor(acc.w, 16);
    acc.w += __shfl_xor(acc.w, 32);

    if (grp == 0) {
        ((float4*)(out + (size_t)n * kD))[sub] = acc;
    }

    // ---- attn probabilities: attn_out[n, l] ----
    // lane (grp, sub) holds w[c] for l = 4c + grp; let sub==c lanes write.
#pragma unroll
    for (int c = 0; c < 5; ++c) {
        if (sub == c) attn_out[(size_t)n * kL + 4 * c + grp] = w[c];
    }
}

extern "C" void kernel_launch(void* const* d_in, const int* in_sizes, int n_in,
                              void* d_out, int out_size, void* d_ws, size_t ws_size,
                              hipStream_t stream) {
    const float* q = (const float*)d_in[0];
    const float* k = (const float*)d_in[1];
    const float* v = (const float*)d_in[2];
    const float* r_pri = (const float*)d_in[3];
    const int* mask = (const int*)d_in[4];

    const int N = in_sizes[0] / (kL * kD);  // 65536
    float* out = (float*)d_out;
    float* attn = out + (size_t)N * kD;

    dim3 block(256);
    dim3 grid((N + 3) / 4);  // 4 rows (waves) per block
    hipLaunchKernelGGL(sdpa_prior_mask_kernel, grid, block, 0, stream,
                       q, k, v, r_pri, mask, out, attn, N);
}